// Round 8
// baseline (31.200 us; speedup 1.0000x reference)
//
#include <hip/hip_runtime.h>
#include <math.h>

#define N_NODES 10000
#define N_REL   500
#define H       128
#define L       128

#define TN    20     // n-tile: 500 * 20 = 10000 exactly
#define NBLK  500    // grid of k_main (2 blocks/CU)
#define PSTR  512    // psum row stride

__device__ __forceinline__ float waveReduceSum(float v) {
    #pragma unroll
    for (int m = 1; m < 64; m <<= 1) v += __shfl_xor(v, m, 64);
    return v;
}

__device__ __forceinline__ void gload16(const float* g, float* l) {
    __builtin_amdgcn_global_load_lds((const __attribute__((address_space(1))) void*)g,
                                     (__attribute__((address_space(3))) void*)l, 16, 0, 0);
}

// --- K0: per-node inverse norms (blocks 0..2499) + query rows (2500..2531) --
__global__ __launch_bounds__(256) void k_prep(const float* __restrict__ node,
                                              const float* __restrict__ rel,
                                              const int* __restrict__ eidx,
                                              const int* __restrict__ ridx,
                                              float* __restrict__ invn,
                                              float* __restrict__ query) {
    int wav  = threadIdx.x >> 6;
    int lane = threadIdx.x & 63;
    if (blockIdx.x < 2500) {
        int row = blockIdx.x * 4 + wav;             // < 10000 always
        float2 v = *reinterpret_cast<const float2*>(node + row * H + lane * 2);
        float ss = waveReduceSum(v.x * v.x + v.y * v.y);
        if (lane == 0) invn[row] = 1.0f / fmaxf(sqrtf(ss), 1e-12f);
    } else {
        int l = (blockIdx.x - 2500) * 4 + wav;      // < 128 always
        int ei = eidx[l], ri = ridx[l];
        float2 e = *reinterpret_cast<const float2*>(node + ei * H + lane * 2);
        float inve = 1.0f / fmaxf(sqrtf(waveReduceSum(e.x * e.x + e.y * e.y)), 1e-12f);
        float2 r = *reinterpret_cast<const float2*>(rel + ri * H + lane * 2);
        float invr = 1.0f / fmaxf(sqrtf(waveReduceSum(r.x * r.x + r.y * r.y)), 1e-12f);
        float2 q;
        q.x = e.x * inve + r.x * invr;
        q.y = e.y * inve + r.y * invr;
        *reinterpret_cast<float2*>(query + l * H + lane * 2) = q;
    }
}

// --- K1: 128x20 exp(L1-dist) tile + psum -----------------------------------
// q from LDS (staged via global_load_lds, content swizzle g(row)=((row&7)<<2));
// e straight from global (L1-hot 10 KB), scaled by invn in-register.
// Waves split h 4x32; lane tile 8l x 5n: l = grp+16i, n = nl+4j.
__global__ __launch_bounds__(256, 2) void k_main(const float* __restrict__ node,
                                                 const float* __restrict__ invn,
                                                 const float* __restrict__ query,
                                                 float* __restrict__ out,
                                                 float* __restrict__ psum) {
    __shared__ union {
        float qs[L * H];            // 64 KB  (main-loop phase)
        float red[4][128][21];      // 43 KB  (merge phase, aliases qs)
    } u;

    const int tid  = threadIdx.x;
    const int w    = tid >> 6;          // wave id = h-segment
    const int lane = tid & 63;
    const int grp  = lane >> 2;         // 0..15
    const int nl   = lane & 3;          // 0..3
    const int nb   = blockIdx.x * TN;   // exact, no bounds checks
    const int hs   = w * 32;

    // ---- stage qs via DMA (pre-swizzled source), 16 instrs/wave ----
    {
        const int c0   = (lane & 31) << 2;
        const int roff = lane >> 5;
        const int rq   = w * 32;
        #pragma unroll
        for (int k = 0; k < 16; ++k) {
            int r = rq + k * 2;
            int row = r + roff;
            int g = (row & 7) << 2;
            gload16(query + row * H + (c0 ^ g), &u.qs[r * H]);
        }
    }

    // ---- e-row bases + inverse norms into registers (overlaps DMA) ----
    const float* eb[5];
    float sj[5];
    #pragma unroll
    for (int j = 0; j < 5; ++j) {
        int row = nb + nl + 4 * j;
        eb[j] = node + (size_t)row * H + hs;
        sj[j] = invn[row];
    }
    __syncthreads();   // drains qs DMA

    // ---- main loop: 8 h-quads; q from LDS, e from global (L1-hot) ----
    const int gq = (grp & 7) << 2;
    float acc[8][5] = {};

    #pragma unroll
    for (int hc = 0; hc < 8; ++hc) {
        const int h = hs + (hc << 2);
        float4 qf[8], ef[5];
        #pragma unroll
        for (int i = 0; i < 8; ++i)
            qf[i] = *reinterpret_cast<const float4*>(&u.qs[(grp + 16 * i) * H + (h ^ gq)]);
        #pragma unroll
        for (int j = 0; j < 5; ++j) {
            float4 t = *reinterpret_cast<const float4*>(eb[j] + (hc << 2));
            ef[j].x = t.x * sj[j]; ef[j].y = t.y * sj[j];
            ef[j].z = t.z * sj[j]; ef[j].w = t.w * sj[j];
        }
        #pragma unroll
        for (int i = 0; i < 8; ++i)
            #pragma unroll
            for (int j = 0; j < 5; ++j)
                acc[i][j] += fabsf(qf[i].x - ef[j].x) + fabsf(qf[i].y - ef[j].y)
                           + fabsf(qf[i].z - ef[j].z) + fabsf(qf[i].w - ef[j].w);
    }

    // ---- merge 4 h-segment partials through LDS (aliases qs) ----
    __syncthreads();
    #pragma unroll
    for (int i = 0; i < 8; ++i)
        #pragma unroll
        for (int j = 0; j < 5; ++j)
            u.red[w][grp + 16 * i][nl + 4 * j] = acc[i][j];
    __syncthreads();

    // ---- epilogue: exp (no max: dist<=~34, f32-safe), store, psum ----
    {
        const int l  = tid >> 1;
        const int n0 = (tid & 1) * 10;
        float p[10];
        float rs = 0.f;
        #pragma unroll
        for (int k = 0; k < 10; ++k) {
            float d = u.red[0][l][n0 + k] + u.red[1][l][n0 + k]
                    + u.red[2][l][n0 + k] + u.red[3][l][n0 + k];
            p[k] = __expf(d);
            rs += p[k];
        }
        float* po = out + (size_t)l * N_NODES + nb + n0;
        #pragma unroll
        for (int k = 0; k < 5; ++k)
            *reinterpret_cast<float2*>(po + 2 * k) = make_float2(p[2 * k], p[2 * k + 1]);
        rs += __shfl_xor(rs, 1, 64);
        if ((tid & 1) == 0) psum[l * PSTR + blockIdx.x] = rs;
    }
}

// --- K2: finish softmax: per-row sum of 500 partials, scale ----------------
__global__ __launch_bounds__(256) void k_finish(float* __restrict__ out,
                                                const float* __restrict__ psum) {
    __shared__ float red[4];
    int l = blockIdx.y;
    int tid = threadIdx.x;
    const float* ps = psum + l * PSTR;
    float s = ps[tid] + (tid < NBLK - 256 ? ps[tid + 256] : 0.f);
    #pragma unroll
    for (int m = 1; m < 64; m <<= 1) s += __shfl_xor(s, m, 64);
    if ((tid & 63) == 0) red[tid >> 6] = s;
    __syncthreads();
    float inv = 1.0f / (red[0] + red[1] + red[2] + red[3]);

    int n4 = blockIdx.x * 256 + tid;           // float4 idx within row (<2500)
    if (n4 < 2500) {
        float4* o = reinterpret_cast<float4*>(out) + (size_t)l * 2500 + n4;
        float4 v = *o;
        v.x *= inv; v.y *= inv; v.z *= inv; v.w *= inv;
        *o = v;
    }
}

extern "C" void kernel_launch(void* const* d_in, const int* in_sizes, int n_in,
                              void* d_out, int out_size, void* d_ws, size_t ws_size,
                              hipStream_t stream) {
    const float* node = (const float*)d_in[0];
    const float* rel  = (const float*)d_in[1];
    const int*   eidx = (const int*)d_in[2];
    const int*   ridx = (const int*)d_in[3];
    float* out = (float*)d_out;

    float* invn  = (float*)d_ws;              // 10000 floats
    float* query = (float*)d_ws + 10240;      // 16384 floats
    float* psum  = (float*)d_ws + 26624;      // 128*512 floats

    k_prep<<<2532, 256, 0, stream>>>(node, rel, eidx, ridx, invn, query);
    k_main<<<NBLK, 256, 0, stream>>>(node, invn, query, out, psum);

    dim3 gridC((2500 + 255) / 256, L);        // 10 x 128
    k_finish<<<gridC, 256, 0, stream>>>(out, psum);
}